// Round 7
// baseline (487.961 us; speedup 1.0000x reference)
//
#include <hip/hip_runtime.h>
#include <cmath>

#define NTOT 16384
#define NBATCH 8
#define NPRE 900
#define NPOST 64

// ---------------------------------------------------------------------------
// K1: fused MLP  h = relu(BN(W1@feat + b1)); off = W2@h + b2;
//     writes prop_out[b][n][4] = {xyz+off[0:3], off[3]} into d_out.
// fp32 GEMM, BM=128 BN=256 BK=32, 8x16 per-thread (0.75 B/FMA from LDS),
// double-buffered 96KB dynamic LDS, async global_load_lds staging.
// A-tile stored as [m][8 k4-slots] with slot = k4 ^ (tr&7) XOR swizzle
// (applied to per-lane global SOURCE and to the READ index; LDS dest linear)
// so the 4 broadcast A-addresses per wave hit disjoint bank groups.
// FMA chain is k-ascending per acc element -> bit-identical to prior rounds.
// ---------------------------------------------------------------------------
#if __has_builtin(__builtin_amdgcn_global_load_lds)
#define HAVE_GLDS 1
#define GLDS16(g, l)                                                     \
  __builtin_amdgcn_global_load_lds(                                      \
      (const __attribute__((address_space(1))) void*)(g),                \
      (__attribute__((address_space(3))) void*)(l), 16, 0, 0)
#else
#define HAVE_GLDS 0
#endif

__device__ __forceinline__ float f4c(const float4& v, int kk) {
  return kk == 0 ? v.x : kk == 1 ? v.y : kk == 2 ? v.z : v.w;
}

__global__ __launch_bounds__(256) void mlp_kernel(
    const float* __restrict__ feat, const float* __restrict__ xyz,
    const float* __restrict__ W1, const float* __restrict__ b1,
    const float* __restrict__ gamma, const float* __restrict__ beta,
    const float* __restrict__ rmean, const float* __restrict__ rvar,
    const float* __restrict__ W2, const float* __restrict__ b2,
    float* __restrict__ prop) {
  extern __shared__ float4 smem4[];
  float* smem = (float*)smem4;
  // layout (floats): As[2][4096] @ 0, Bs[2][8192] @ 8192
  const int b  = blockIdx.y;
  const int n0 = blockIdx.x * 256;
  const int tid = threadIdx.x;
  const int tr = tid >> 4, tc = tid & 15;        // tr: 16 M-groups, tc: 16 N-groups
  const int w = tid >> 6, l = tid & 63;          // wave, lane
  const float* fb = feat + (size_t)b * 256 * NTOT;

  float acc[8][16];
#pragma unroll
  for (int r = 0; r < 8; ++r)
#pragma unroll
    for (int c = 0; c < 16; ++c) acc[r][c] = 0.f;

#if !HAVE_GLDS
  float4 rA[4], rB[8];
#endif

  // ---- staging address helpers (shared by both paths) ----
  // A: issue q in 0..3 covers m-rows w*32+q*8 .. +7 (8 rows x 8 slots x 16B)
  //    lane l -> m = base + (l>>3), slot = l&7, k4 = slot ^ ((m>>3)&7)
  // B: issue q in 0..7 covers k-row w*8+q (256 floats), lane l -> +l*4
#define A_SRC(kt_, q_)                                                    \
  (W1 + (size_t)(w * 32 + (q_) * 8 + (l >> 3)) * 256 + (kt_) * 32 +       \
   (((l & 7) ^ (((w * 32 + (q_) * 8 + (l >> 3)) >> 3) & 7)) * 4))
#define A_DST(buf_, q_) (smem + (size_t)(buf_) * 4096 + (w * 32 + (q_) * 8) * 8 * 4)
#define B_SRC(kt_, q_) (fb + (size_t)((kt_) * 32 + w * 8 + (q_)) * NTOT + n0 + l * 4)
#define B_DST(buf_, q_) (smem + 8192 + (size_t)(buf_) * 8192 + (w * 8 + (q_)) * 256)

  // ---- prologue: stage buffer 0 for kt=0 ----
#if HAVE_GLDS
#pragma unroll
  for (int q = 0; q < 4; ++q) GLDS16(A_SRC(0, q), A_DST(0, q));
#pragma unroll
  for (int q = 0; q < 8; ++q) GLDS16(B_SRC(0, q), B_DST(0, q));
#else
#pragma unroll
  for (int q = 0; q < 4; ++q) rA[q] = *(const float4*)A_SRC(0, q);
#pragma unroll
  for (int q = 0; q < 8; ++q) rB[q] = *(const float4*)B_SRC(0, q);
#pragma unroll
  for (int q = 0; q < 4; ++q) *(float4*)(A_DST(0, q) + l * 4) = rA[q];
#pragma unroll
  for (int q = 0; q < 8; ++q) *(float4*)(B_DST(0, q) + l * 4) = rB[q];
#endif
  __syncthreads();

  for (int kt = 0; kt < 8; ++kt) {
    const int buf = kt & 1;
    // issue next tile's staging before compute (latency hides under FMAs)
    if (kt + 1 < 8) {
#if HAVE_GLDS
#pragma unroll
      for (int q = 0; q < 4; ++q) GLDS16(A_SRC(kt + 1, q), A_DST(buf ^ 1, q));
#pragma unroll
      for (int q = 0; q < 8; ++q) GLDS16(B_SRC(kt + 1, q), B_DST(buf ^ 1, q));
#else
#pragma unroll
      for (int q = 0; q < 4; ++q) rA[q] = *(const float4*)A_SRC(kt + 1, q);
#pragma unroll
      for (int q = 0; q < 8; ++q) rB[q] = *(const float4*)B_SRC(kt + 1, q);
#endif
    }
    const float* Asb = smem + (size_t)buf * 4096;
    const float* Bsb = smem + 8192 + (size_t)buf * 8192;
    for (int k4 = 0; k4 < 8; ++k4) {
      float4 a4[8];
#pragma unroll
      for (int r = 0; r < 8; ++r)
        a4[r] = *(const float4*)(Asb + ((tr * 8 + r) * 8 + (k4 ^ (tr & 7))) * 4);
#pragma unroll
      for (int kk = 0; kk < 4; ++kk) {
        const int k = k4 * 4 + kk;
        float bb[16];
        *(float4*)&bb[0]  = *(const float4*)(Bsb + k * 256 + tc * 4);
        *(float4*)&bb[4]  = *(const float4*)(Bsb + k * 256 + 64 + tc * 4);
        *(float4*)&bb[8]  = *(const float4*)(Bsb + k * 256 + 128 + tc * 4);
        *(float4*)&bb[12] = *(const float4*)(Bsb + k * 256 + 192 + tc * 4);
#pragma unroll
        for (int r = 0; r < 8; ++r) {
          const float av = f4c(a4[r], kk);
#pragma unroll
          for (int c = 0; c < 16; ++c) acc[r][c] = fmaf(av, bb[c], acc[r][c]);
        }
      }
    }
#if !HAVE_GLDS
    if (kt + 1 < 8) {
#pragma unroll
      for (int q = 0; q < 4; ++q) *(float4*)(A_DST(buf ^ 1, q) + l * 4) = rA[q];
#pragma unroll
      for (int q = 0; q < 8; ++q) *(float4*)(B_DST(buf ^ 1, q) + l * 4) = rB[q];
    }
#endif
    __syncthreads();
  }

  // ---- epilogue: bias + BN + relu + W2 partials (same exprs/order as before)
  float po[4][16];
#pragma unroll
  for (int kk = 0; kk < 4; ++kk)
#pragma unroll
    for (int c = 0; c < 16; ++c) po[kk][c] = 0.f;
#pragma unroll
  for (int r = 0; r < 8; ++r) {
    const int row = tr * 8 + r;
    const float inv = gamma[row] / sqrtf(rvar[row] + 1e-5f);
    const float sh  = beta[row] - rmean[row] * inv;
    const float bb1 = b1[row];
    float w2v[4];
#pragma unroll
    for (int kk = 0; kk < 4; ++kk) w2v[kk] = W2[kk * 128 + row];
#pragma unroll
    for (int c = 0; c < 16; ++c) {
      float h = (acc[r][c] + bb1) * inv + sh;
      h = fmaxf(h, 0.f);
#pragma unroll
      for (int kk = 0; kk < 4; ++kk) po[kk][c] += w2v[kk] * h;
    }
  }
  float* po_lds = smem;                 // [16][4][256] = 16384 floats
#pragma unroll
  for (int kk = 0; kk < 4; ++kk)
#pragma unroll
    for (int c = 0; c < 16; ++c) {
      const int col = (c >> 2) * 64 + tc * 4 + (c & 3);
      po_lds[((tr * 4 + kk) * 256) + col] = po[kk][c];
    }
  __syncthreads();
  float* off_lds = smem + 16384;        // [4][256]
#pragma unroll
  for (int it = 0; it < 4; ++it) {
    const int idx = tid + it * 256;
    const int kk = idx >> 8, col = idx & 255;
    float sum = b2[kk];
#pragma unroll
    for (int t2 = 0; t2 < 16; ++t2) sum += po_lds[((t2 * 4 + kk) * 256) + col];
    off_lds[kk * 256 + col] = sum;
  }
  __syncthreads();
  {
    const int n = n0 + tid;
    const float* sx = xyz + ((size_t)b * NTOT + n) * 3;
    float4 o;
    o.x = sx[0] + off_lds[0 * 256 + tid];
    o.y = sx[1] + off_lds[1 * 256 + tid];
    o.z = sx[2] + off_lds[2 * 256 + tid];
    o.w = off_lds[3 * 256 + tid];
    *(float4*)(prop + ((size_t)b * NTOT + n) * 4) = o;
  }
#undef A_SRC
#undef A_DST
#undef B_SRC
#undef B_DST
}

// ---------------------------------------------------------------------------
// shared clip routine: register-only Sutherland-Hodgman, 8-slot cndmask push
// chains (exact reference semantics incl. OOB drop / gather clamp).
// ---------------------------------------------------------------------------
__device__ __forceinline__ float polyclip_reg(
    float s0x, float s0y, float s1x, float s1y,
    float s2x, float s2y, float s3x, float s3y,
    const float cjx[4], const float cjy[4]) {
#pragma clang fp contract(off)
  float vx[8], vy[8];
  vx[0] = s0x; vy[0] = s0y; vx[1] = s1x; vy[1] = s1y;
  vx[2] = s2x; vy[2] = s2y; vx[3] = s3x; vy[3] = s3y;
#pragma unroll
  for (int v = 4; v < 8; ++v) { vx[v] = 0.f; vy[v] = 0.f; }
  int cnt = 4;
#pragma unroll
  for (int e = 0; e < 4; ++e) {
    const float ax = cjx[e], ay = cjy[e];
    const float bx = cjx[(e + 1) & 3], by = cjy[(e + 1) & 3];
    const float nx = bx - ax, ny = by - ay;
    float d[8];
#pragma unroll
    for (int v = 0; v < 8; ++v) d[v] = nx * (vy[v] - ay) - ny * (vx[v] - ax);
    float ox[8], oy[8];
#pragma unroll
    for (int v = 0; v < 8; ++v) { ox[v] = 0.f; oy[v] = 0.f; }
    int oc = 0;
#pragma unroll
    for (int v = 0; v < 8; ++v) {
      const bool valid = v < cnt;
      float nvx, nvy, dn;
      if (v == 7) {
        const bool big = cnt > 8;
        nvx = big ? vx[7] : vx[0]; nvy = big ? vy[7] : vy[0]; dn = big ? d[7] : d[0];
      } else {
        const bool wrap = (v + 1 >= cnt);
        nvx = wrap ? vx[0] : vx[v + 1];
        nvy = wrap ? vy[0] : vy[v + 1];
        dn  = wrap ? d[0]  : d[v + 1];
      }
      const float dc = d[v];
      const bool inc = dc >= 0.f, inn = dn >= 0.f;
      const bool e1 = valid && inc;
#pragma unroll
      for (int s2 = 0; s2 < 8; ++s2) {
        const bool w_ = e1 && (oc == s2);
        ox[s2] = w_ ? vx[v] : ox[s2];
        oy[s2] = w_ ? vy[v] : oy[s2];
      }
      oc += e1 ? 1 : 0;
      const bool e2 = valid && (inc != inn);
      const float den = dc - dn;
      const float t = dc / ((den == 0.f) ? 1.0f : den);
      const float ipx = vx[v] + t * (nvx - vx[v]);
      const float ipy = vy[v] + t * (nvy - vy[v]);
#pragma unroll
      for (int s2 = 0; s2 < 8; ++s2) {
        const bool w_ = e2 && (oc == s2);
        ox[s2] = w_ ? ipx : ox[s2];
        oy[s2] = w_ ? ipy : oy[s2];
      }
      oc += e2 ? 1 : 0;
    }
#pragma unroll
    for (int v = 0; v < 8; ++v) { vx[v] = ox[v]; vy[v] = oy[v]; }
    cnt = oc;
  }
  float s = 0.f;
#pragma unroll
  for (int v = 0; v < 8; ++v) {
    const bool valid = (v < cnt) && (cnt >= 3);
    float jx, jy;
    if (v == 7) {
      const bool big = cnt > 8;
      jx = big ? vx[7] : vx[0]; jy = big ? vy[7] : vy[0];
    } else {
      const bool wrap = (v + 1 >= cnt);
      jx = wrap ? vx[0] : vx[v + 1]; jy = wrap ? vy[0] : vy[v + 1];
    }
    s += valid ? (vx[v] * jy - jx * vy[v]) : 0.f;
  }
  return fabsf(s) * 0.5f;
}

__device__ __forceinline__ bool pair_suppressed(
    const float* __restrict__ corners, const float* __restrict__ areas,
    int b, int i, int j) {
  const float* ci = corners + ((size_t)b * NPRE + i) * 8;
  const float* cj = corners + ((size_t)b * NPRE + j) * 8;
  float cjx[4], cjy[4];
#pragma unroll
  for (int q = 0; q < 4; ++q) { cjx[q] = cj[2 * q]; cjy[q] = cj[2 * q + 1]; }
  const float inter = polyclip_reg(ci[0], ci[1], ci[2], ci[3],
                                   ci[4], ci[5], ci[6], ci[7], cjx, cjy);
  const float ai = areas[(size_t)b * NPRE + i];
  const float aj = areas[(size_t)b * NPRE + j];
  const float iou = inter / fmaxf(ai + aj - inter, 1e-8f);
  return iou > 0.85f;
}

// ---------------------------------------------------------------------------
// K2: exact top-NPRE selection via threshold bisection on sigmoid bits with
//     early exit; bitonic sort of <=1024 candidates (key<<32 | ~idx).
//     Emits corners/area/aabb and zeroes the pairgen worklist counters.
// ---------------------------------------------------------------------------
__global__ __launch_bounds__(1024) void select_kernel(
    const float* __restrict__ cla, const float* __restrict__ prop,
    const float* __restrict__ tmpl, float* __restrict__ selbox,
    float* __restrict__ corners, float* __restrict__ areas,
    float* __restrict__ aabb, int* __restrict__ wlcnt) {
  __shared__ unsigned red[17];
  __shared__ int cnt_lds;
  __shared__ unsigned long long cand[1024];
  const int b = blockIdx.x, tid = threadIdx.x;
  if (tid == 0) wlcnt[b] = 0;
  unsigned key[16];
#pragma unroll
  for (int q = 0; q < 16; ++q) {
    const float x = cla[(size_t)b * NTOT + q * 1024 + tid];
    key[q] = __float_as_uint(1.0f / (1.0f + expf(-x)));
  }
  unsigned lo = 0u, hi = 0xFFFFFFFFu;
  unsigned T = 0u;
  bool done = false;
  while (!done && (hi - lo > 1u)) {
    const unsigned mid = lo + ((hi - lo) >> 1);
    int c = 0;
#pragma unroll
    for (int q = 0; q < 16; ++q) c += (key[q] >= mid) ? 1 : 0;
#pragma unroll
    for (int off = 32; off > 0; off >>= 1) c += __shfl_down(c, off);
    __syncthreads();
    if ((tid & 63) == 0) red[tid >> 6] = (unsigned)c;
    __syncthreads();
    if (tid == 0) {
      unsigned s = 0;
      for (int w2 = 0; w2 < 16; ++w2) s += red[w2];
      red[16] = s;
    }
    __syncthreads();
    const unsigned cntv = red[16];
    if (cntv >= NPRE && cntv <= 1024) { T = mid; done = true; }
    else if (cntv >= NPRE) lo = mid;
    else hi = mid;
  }
  if (!done) T = lo;
  if (tid == 0) cnt_lds = 0;
  cand[tid] = 0ull;
  __syncthreads();
#pragma unroll
  for (int q = 0; q < 16; ++q) {
    if (key[q] >= T) {
      const int pos = atomicAdd(&cnt_lds, 1);
      if (pos < 1024)
        cand[pos] = ((unsigned long long)key[q] << 32) |
                    (unsigned long long)(0xFFFFFFFFu - (unsigned)(q * 1024 + tid));
    }
  }
  __syncthreads();
  for (int k = 2; k <= 1024; k <<= 1) {
    for (int j = k >> 1; j > 0; j >>= 1) {
      if (tid < 512) {
        const int i = ((tid & ~(j - 1)) << 1) | (tid & (j - 1));
        const int l = i | j;
        const unsigned long long Pi = cand[i], Pl = cand[l];
        const bool asc = (i & k) == 0;
        if ((Pi < Pl) == asc) { cand[i] = Pl; cand[l] = Pi; }
      }
      __syncthreads();
    }
  }
  if (tid < NPRE) {
    const unsigned long long p = cand[tid];
    const int idx = (int)(0xFFFFFFFFu - (unsigned)(p & 0xFFFFFFFFull));
    const float score = __uint_as_float((unsigned)(p >> 32));
    const float4 pv = *(const float4*)(prop + ((size_t)b * NTOT + idx) * 4);
    const float d3 = tmpl[b * 7 + 3], d4 = tmpl[b * 7 + 4], d5 = tmpl[b * 7 + 5];
    const size_t o8 = ((size_t)b * NPRE + tid) * 8;
    selbox[o8 + 0] = pv.x; selbox[o8 + 1] = pv.y; selbox[o8 + 2] = pv.z;
    selbox[o8 + 3] = d3;   selbox[o8 + 4] = d4;   selbox[o8 + 5] = d5;
    selbox[o8 + 6] = pv.w; selbox[o8 + 7] = score;
    {
#pragma clang fp contract(off)
      const float cu = pv.x, cv = pv.z;
      const float hl = d5 * 0.5f, hw = d4 * 0.5f;
      const float x1 = cu - hl, y1 = cv - hw, x2 = cu + hl, y2 = cv + hw;
      const float cx = (x1 + x2) * 0.5f, cy = (y1 + y2) * 0.5f;
      const float hx = (x2 - x1) * 0.5f, hy = (y2 - y1) * 0.5f;
      const float cr = cosf(pv.w), sr = sinf(pv.w);
      const float lx[4] = {-hx, hx, hx, -hx};
      const float ly[4] = {-hy, -hy, hy, hy};
      float bx0 = 1e30f, by0 = 1e30f, bx1 = -1e30f, by1 = -1e30f;
#pragma unroll
      for (int q = 0; q < 4; ++q) {
        const float X = cx + cr * lx[q] - sr * ly[q];
        const float Y = cy + sr * lx[q] + cr * ly[q];
        corners[o8 + 2 * q]     = X;
        corners[o8 + 2 * q + 1] = Y;
        bx0 = fminf(bx0, X); by0 = fminf(by0, Y);
        bx1 = fmaxf(bx1, X); by1 = fmaxf(by1, Y);
      }
      areas[(size_t)b * NPRE + tid] = (x2 - x1) * (y2 - y1);
      float4 bb; bb.x = bx0; bb.y = by0; bb.z = bx1; bb.w = by1;
      *(float4*)(aabb + ((size_t)b * NPRE + tid) * 4) = bb;
    }
  }
}

// ---------------------------------------------------------------------------
// K3a: pairgen — AABB quick-test (conservative, margin >> fp noise), compact
// passing pairs into per-batch worklist; zero own sup row. Overflow pairs
// are clipped inline (correctness guard).
// ---------------------------------------------------------------------------
__global__ __launch_bounds__(256) void pairgen_kernel(
    const float* __restrict__ aabb, const float* __restrict__ areas,
    const float* __restrict__ corners, unsigned long long* __restrict__ sup,
    unsigned* __restrict__ wl, int* __restrict__ wlcnt, int cap) {
  __shared__ int wsum[4];
  __shared__ int base_s;
  const int i = blockIdx.x, b = blockIdx.y, tid = threadIdx.x;
  if (tid < 16) sup[((size_t)b * NPRE + i) * 16 + tid] = 0ull;
  const float4 bi = *(const float4*)(aabb + ((size_t)b * NPRE + i) * 4);
  const float ai = areas[(size_t)b * NPRE + i];
  bool pass[4];
  int pc = 0;
#pragma unroll
  for (int c = 0; c < 4; ++c) {
    const int j = c * 256 + tid;
    bool p = false;
    if (j > i && j < NPRE) {
      const float4 bj = *(const float4*)(aabb + ((size_t)b * NPRE + j) * 4);
      const float aj = areas[(size_t)b * NPRE + j];
      const float ow = fminf(bi.z, bj.z) - fmaxf(bi.x, bj.x);
      const float oh = fminf(bi.w, bj.w) - fmaxf(bi.y, bj.y);
      const float ov = fmaxf(ow, 0.f) * fmaxf(oh, 0.f);
      p = (ov >= 0.45f * (ai + aj));
    }
    pass[c] = p;
    pc += p ? 1 : 0;
  }
  int inc = pc;
#pragma unroll
  for (int d2 = 1; d2 < 64; d2 <<= 1) {
    const int u = __shfl_up(inc, d2);
    if ((tid & 63) >= d2) inc += u;
  }
  if ((tid & 63) == 63) wsum[tid >> 6] = inc;
  __syncthreads();
  if (tid == 0) {
    const int tot = wsum[0] + wsum[1] + wsum[2] + wsum[3];
    base_s = (tot > 0) ? atomicAdd(&wlcnt[b], tot) : 0;
  }
  __syncthreads();
  int wbase = 0;
#pragma unroll
  for (int w = 0; w < 4; ++w)
    if (w < (tid >> 6)) wbase += wsum[w];
  int myoff = base_s + wbase + (inc - pc);
#pragma unroll
  for (int c = 0; c < 4; ++c) {
    if (pass[c]) {
      const int j = c * 256 + tid;
      const int pos = myoff++;
      if (pos < cap) {
        wl[(size_t)b * cap + pos] = (unsigned)((i << 10) | j);
      } else {
        if (pair_suppressed(corners, areas, b, i, j))
          atomicOr(&sup[((size_t)b * NPRE + i) * 16 + (j >> 6)],
                   1ull << (j & 63));
      }
    }
  }
}

// ---------------------------------------------------------------------------
// K3b: clip — dense worklist, one pair per lane, exact clip, atomicOr bit.
// ---------------------------------------------------------------------------
__global__ __launch_bounds__(256) void clip_kernel(
    const float* __restrict__ corners, const float* __restrict__ areas,
    const unsigned* __restrict__ wl, const int* __restrict__ wlcnt, int cap,
    unsigned long long* __restrict__ sup) {
  const int b = blockIdx.y, tid = threadIdx.x;
  const int n = min(wlcnt[b], cap);
  for (int idx = blockIdx.x * 256 + tid; idx < n; idx += gridDim.x * 256) {
    const unsigned e = wl[(size_t)b * cap + idx];
    const int i = (int)(e >> 10), j = (int)(e & 1023u);
    if (pair_suppressed(corners, areas, b, i, j))
      atomicOr(&sup[((size_t)b * NPRE + i) * 16 + (j >> 6)], 1ull << (j & 63));
  }
}

// ---------------------------------------------------------------------------
// K4: sequential NMS. LDS-staged sup matrix, 4-deep static prefetch.
// ---------------------------------------------------------------------------
#define NMS_ROWS 904
__global__ __launch_bounds__(1024) void nms_kernel(
    const unsigned long long* __restrict__ sup,
    unsigned long long* __restrict__ keepw) {
  extern __shared__ unsigned long long rows[];   // NMS_ROWS*16*8 = 115,712 B
  const int b = blockIdx.x, tid = threadIdx.x;
  const unsigned long long* srow = sup + (size_t)b * NPRE * 16;
  for (int q = tid; q < NMS_ROWS * 16; q += 1024)
    rows[q] = (q < NPRE * 16) ? srow[q] : 0ull;
  __syncthreads();
  if (tid < 64) {
    const int lane = tid;
    const bool ld = lane < 16;
    unsigned long long kw = 0ull;
    if (lane < 14) kw = ~0ull;
    else if (lane == 14) kw = 0xFull;            // bits 896..899
    unsigned long long r0 = ld ? rows[0 * 16 + lane] : 0ull;
    unsigned long long r1 = ld ? rows[1 * 16 + lane] : 0ull;
    unsigned long long r2 = ld ? rows[2 * 16 + lane] : 0ull;
    unsigned long long r3 = ld ? rows[3 * 16 + lane] : 0ull;
#define NMS_STEP(ii, bufv)                                            \
    {                                                                 \
      const unsigned long long w = __shfl(kw, (ii) >> 6);             \
      if ((w >> ((ii) & 63)) & 1ull) kw &= ~(bufv);                   \
      bufv = ld ? rows[((ii) + 4) * 16 + lane] : 0ull;                \
    }
    for (int i = 0; i < NPRE; i += 4) {
      NMS_STEP(i + 0, r0)
      NMS_STEP(i + 1, r1)
      NMS_STEP(i + 2, r2)
      NMS_STEP(i + 3, r3)
    }
#undef NMS_STEP
    if (lane < 15) keepw[b * 16 + lane] = kw;
  }
}

// ---------------------------------------------------------------------------
// K5: zero outputs, rank kept boxes, scatter top-64.
// ---------------------------------------------------------------------------
__global__ __launch_bounds__(128) void out_kernel(
    const float* __restrict__ selbox,
    const unsigned long long* __restrict__ keepw, float* __restrict__ out) {
  const int b = blockIdx.x, t = threadIdx.x;
  float* retb = out + (size_t)b * (NPOST * 7);
  float* rets = out + (size_t)NBATCH * NPOST * 7 + (size_t)b * NPOST;
  float* cent = out + (size_t)NBATCH * NPOST * 7 + (size_t)NBATCH * NPOST +
                (size_t)NBATCH * NTOT * 4 + (size_t)b * (NPOST * 3);
  for (int q = t; q < NPOST * 7; q += 128) retb[q] = 0.f;
  if (t < NPOST) rets[t] = 0.f;
  for (int q = t; q < NPOST * 3; q += 128) cent[q] = 0.f;
  __syncthreads();
  if (t < 64) {
    const unsigned long long kws = (t < 15) ? keepw[b * 16 + t] : 0ull;
    const int pc = __popcll(kws);
    int inc = pc;
    for (int d2 = 1; d2 < 64; d2 <<= 1) {
      const int up = __shfl_up(inc, d2);
      if (t >= d2) inc += up;
    }
    const int ex = inc - pc;
    for (int it = 0; it < 15; ++it) {
      const int i = t + it * 64;
      const int w = (i >> 6) & 63;
      const unsigned long long kword = __shfl(kws, w);
      const int exw = __shfl(ex, w);
      if (i < NPRE) {
        const int bp = i & 63;
        if ((kword >> bp) & 1ull) {
          const int rank =
              exw + __popcll(kword & (((unsigned long long)1 << bp) - 1ull));
          if (rank < NPOST) {
            const float* sb = selbox + ((size_t)b * NPRE + i) * 8;
#pragma unroll
            for (int c = 0; c < 7; ++c) retb[rank * 7 + c] = sb[c];
            rets[rank] = sb[7];
            cent[rank * 3 + 0] = sb[0];
            cent[rank * 3 + 1] = sb[1];
            cent[rank * 3 + 2] = sb[2];
          }
        }
      }
    }
  }
}

// ---------------------------------------------------------------------------
extern "C" void kernel_launch(void* const* d_in, const int* in_sizes, int n_in,
                              void* d_out, int out_size, void* d_ws, size_t ws_size,
                              hipStream_t stream) {
  const float* xyz   = (const float*)d_in[0];
  const float* feat  = (const float*)d_in[1];
  const float* cla   = (const float*)d_in[2];
  const float* tmpl  = (const float*)d_in[3];
  const float* W1    = (const float*)d_in[4];
  const float* b1    = (const float*)d_in[5];
  const float* gamma = (const float*)d_in[6];
  const float* beta  = (const float*)d_in[7];
  const float* rmean = (const float*)d_in[8];
  const float* rvar  = (const float*)d_in[9];
  const float* W2    = (const float*)d_in[10];
  const float* b2    = (const float*)d_in[11];
  float* out  = (float*)d_out;
  float* prop = out + (size_t)NBATCH * NPOST * 7 + (size_t)NBATCH * NPOST;

  char* ws = (char*)d_ws;
  float* selbox  = (float*)(ws);                                   // 230400 B
  float* corners = (float*)(ws + 230400);                          // 230400 B
  float* areas   = (float*)(ws + 460800);                          // 28800 B
  float* aabb    = (float*)(ws + 489600);                          // 115200 B
  unsigned long long* sup   = (unsigned long long*)(ws + 604800);  // 921600 B
  unsigned long long* keepw = (unsigned long long*)(ws + 1526400); // 1024 B
  int* wlcnt = (int*)(ws + 1527424);                               // 32 B
  unsigned* wl = (unsigned*)(ws + 1527456);
  long long avail = (long long)ws_size - 1527456;
  if (avail < 0) avail = 0;
  int cap = (int)(avail / (4 * NBATCH));
  if (cap > 404551) cap = 404551;   // max j>i pairs per batch

  (void)hipFuncSetAttribute((const void*)mlp_kernel,
                            hipFuncAttributeMaxDynamicSharedMemorySize, 98304);
  mlp_kernel<<<dim3(NTOT / 256, NBATCH), 256, 98304, stream>>>(
      feat, xyz, W1, b1, gamma, beta, rmean, rvar, W2, b2, prop);

  select_kernel<<<NBATCH, 1024, 0, stream>>>(cla, prop, tmpl, selbox, corners,
                                             areas, aabb, wlcnt);

  pairgen_kernel<<<dim3(NPRE, NBATCH), 256, 0, stream>>>(
      aabb, areas, corners, sup, wl, wlcnt, cap);

  clip_kernel<<<dim3(64, NBATCH), 256, 0, stream>>>(corners, areas, wl, wlcnt,
                                                    cap, sup);

  (void)hipFuncSetAttribute((const void*)nms_kernel,
                            hipFuncAttributeMaxDynamicSharedMemorySize,
                            NMS_ROWS * 16 * (int)sizeof(unsigned long long));
  nms_kernel<<<NBATCH, 1024, NMS_ROWS * 16 * sizeof(unsigned long long),
               stream>>>(sup, keepw);

  out_kernel<<<NBATCH, 128, 0, stream>>>(selbox, keepw, out);
}

// Round 8
// 468.668 us; speedup vs baseline: 1.0412x; 1.0412x over previous
//
#include <hip/hip_runtime.h>
#include <cmath>

#define NTOT 16384
#define NBATCH 8
#define NPRE 900
#define NPOST 64

// ---------------------------------------------------------------------------
// K1: fused MLP  h = relu(BN(W1@feat + b1)); off = W2@h + b2;
//     writes prop_out[b][n][4] = {xyz+off[0:3], off[3]} into d_out.
// fp32 GEMM, BM=128 BN=256 BK=16, 8x16 per-thread (0.75 B/FMA from LDS),
// double-buffered 48KB compute LDS (68KB alloc incl. epilogue scratch)
// -> 2 blocks/CU, 8 waves/CU, 2 waves/SIMD (the r7 regression was 1 wave/SIMD).
// A-tile stored [m][4 k4-slots], slot = k4 ^ (tr&3) XOR swizzle applied to
// per-lane global SOURCE and READ index; LDS dest linear (rule #21).
// FMA chain k-ascending, same per-thread mapping as r5/r7 -> bit-identical.
// ---------------------------------------------------------------------------
#if __has_builtin(__builtin_amdgcn_global_load_lds)
#define HAVE_GLDS 1
#define GLDS16(g, l)                                                     \
  __builtin_amdgcn_global_load_lds(                                      \
      (const __attribute__((address_space(1))) void*)(g),                \
      (__attribute__((address_space(3))) void*)(l), 16, 0, 0)
#else
#define HAVE_GLDS 0
#endif

__device__ __forceinline__ float f4c(const float4& v, int kk) {
  return kk == 0 ? v.x : kk == 1 ? v.y : kk == 2 ? v.z : v.w;
}

__global__ __launch_bounds__(256) void mlp_kernel(
    const float* __restrict__ feat, const float* __restrict__ xyz,
    const float* __restrict__ W1, const float* __restrict__ b1,
    const float* __restrict__ gamma, const float* __restrict__ beta,
    const float* __restrict__ rmean, const float* __restrict__ rvar,
    const float* __restrict__ W2, const float* __restrict__ b2,
    float* __restrict__ prop) {
  extern __shared__ float4 smem4[];
  float* smem = (float*)smem4;
  // compute layout (floats): As[2][2048] @ 0, Bs[2][4096] @ 4096
  const int b  = blockIdx.y;
  const int n0 = blockIdx.x * 256;
  const int tid = threadIdx.x;
  const int tr = tid >> 4, tc = tid & 15;        // 16 M-groups x 16 N-groups
  const int w = tid >> 6, l = tid & 63;          // wave, lane
  const float* fb = feat + (size_t)b * 256 * NTOT;

  float acc[8][16];
#pragma unroll
  for (int r = 0; r < 8; ++r)
#pragma unroll
    for (int c = 0; c < 16; ++c) acc[r][c] = 0.f;

#if !HAVE_GLDS
  float4 rA[2], rB[4];
#endif

  // ---- staging helpers ----
  // A: per buf 128 rows x 4 slots x 16B = 8KB; 2 issues/thread.
  //    issue q covers rows w*32+q*16 .. +15; lane l -> row = base+(l>>2),
  //    slot = l&3, source k4 = slot ^ ((row>>3)&3)   [involution]
  // B: per buf 16 k-rows x 1KB = 16KB; 4 issues/thread; issue q -> k = w*4+q.
#define A_ROW(q_) (w * 32 + (q_) * 16 + (l >> 2))
#define A_SRC(kt_, q_)                                                    \
  (W1 + (size_t)A_ROW(q_) * 256 + (kt_) * 16 +                            \
   (((l & 3) ^ ((A_ROW(q_) >> 3) & 3)) * 4))
#define A_DST(buf_, q_) (smem + (size_t)(buf_) * 2048 + (w * 32 + (q_) * 16) * 16)
#define B_SRC(kt_, q_) (fb + (size_t)((kt_) * 16 + w * 4 + (q_)) * NTOT + n0 + l * 4)
#define B_DST(buf_, q_) (smem + 4096 + (size_t)(buf_) * 4096 + (w * 4 + (q_)) * 256)

  // ---- prologue: stage buffer 0 for kt=0 ----
#if HAVE_GLDS
#pragma unroll
  for (int q = 0; q < 2; ++q) GLDS16(A_SRC(0, q), A_DST(0, q));
#pragma unroll
  for (int q = 0; q < 4; ++q) GLDS16(B_SRC(0, q), B_DST(0, q));
#else
#pragma unroll
  for (int q = 0; q < 2; ++q) rA[q] = *(const float4*)A_SRC(0, q);
#pragma unroll
  for (int q = 0; q < 4; ++q) rB[q] = *(const float4*)B_SRC(0, q);
#pragma unroll
  for (int q = 0; q < 2; ++q) *(float4*)(A_DST(0, q) + l * 4) = rA[q];
#pragma unroll
  for (int q = 0; q < 4; ++q) *(float4*)(B_DST(0, q) + l * 4) = rB[q];
#endif
  __syncthreads();

  for (int kt = 0; kt < 16; ++kt) {
    const int buf = kt & 1;
    if (kt + 1 < 16) {   // issue next tile's staging; hides under FMAs
#if HAVE_GLDS
#pragma unroll
      for (int q = 0; q < 2; ++q) GLDS16(A_SRC(kt + 1, q), A_DST(buf ^ 1, q));
#pragma unroll
      for (int q = 0; q < 4; ++q) GLDS16(B_SRC(kt + 1, q), B_DST(buf ^ 1, q));
#else
#pragma unroll
      for (int q = 0; q < 2; ++q) rA[q] = *(const float4*)A_SRC(kt + 1, q);
#pragma unroll
      for (int q = 0; q < 4; ++q) rB[q] = *(const float4*)B_SRC(kt + 1, q);
#endif
    }
    const float* Asb = smem + (size_t)buf * 2048;
    const float* Bsb = smem + 4096 + (size_t)buf * 4096;
#pragma unroll
    for (int k4 = 0; k4 < 4; ++k4) {
      float4 a4[8];
#pragma unroll
      for (int r = 0; r < 8; ++r)
        a4[r] = *(const float4*)(Asb + (tr * 8 + r) * 16 + (k4 ^ (tr & 3)) * 4);
#pragma unroll
      for (int kk = 0; kk < 4; ++kk) {
        const int k = k4 * 4 + kk;
        float bb[16];
        *(float4*)&bb[0]  = *(const float4*)(Bsb + k * 256 + tc * 4);
        *(float4*)&bb[4]  = *(const float4*)(Bsb + k * 256 + 64 + tc * 4);
        *(float4*)&bb[8]  = *(const float4*)(Bsb + k * 256 + 128 + tc * 4);
        *(float4*)&bb[12] = *(const float4*)(Bsb + k * 256 + 192 + tc * 4);
#pragma unroll
        for (int r = 0; r < 8; ++r) {
          const float av = f4c(a4[r], kk);
#pragma unroll
          for (int c = 0; c < 16; ++c) acc[r][c] = fmaf(av, bb[c], acc[r][c]);
        }
      }
    }
#if !HAVE_GLDS
    if (kt + 1 < 16) {
#pragma unroll
      for (int q = 0; q < 2; ++q) *(float4*)(A_DST(buf ^ 1, q) + l * 4) = rA[q];
#pragma unroll
      for (int q = 0; q < 4; ++q) *(float4*)(B_DST(buf ^ 1, q) + l * 4) = rB[q];
    }
#endif
    __syncthreads();
  }

  // ---- epilogue: bias + BN + relu + W2 partials (same exprs/order) ----
  float po[4][16];
#pragma unroll
  for (int kk = 0; kk < 4; ++kk)
#pragma unroll
    for (int c = 0; c < 16; ++c) po[kk][c] = 0.f;
#pragma unroll
  for (int r = 0; r < 8; ++r) {
    const int row = tr * 8 + r;
    const float inv = gamma[row] / sqrtf(rvar[row] + 1e-5f);
    const float sh  = beta[row] - rmean[row] * inv;
    const float bb1 = b1[row];
    float w2v[4];
#pragma unroll
    for (int kk = 0; kk < 4; ++kk) w2v[kk] = W2[kk * 128 + row];
#pragma unroll
    for (int c = 0; c < 16; ++c) {
      float h = (acc[r][c] + bb1) * inv + sh;
      h = fmaxf(h, 0.f);
#pragma unroll
      for (int kk = 0; kk < 4; ++kk) po[kk][c] += w2v[kk] * h;
    }
  }
  float* po_lds = smem;                 // [16][4][256] = 16384 floats (64KB)
#pragma unroll
  for (int kk = 0; kk < 4; ++kk)
#pragma unroll
    for (int c = 0; c < 16; ++c) {
      const int col = (c >> 2) * 64 + tc * 4 + (c & 3);
      po_lds[((tr * 4 + kk) * 256) + col] = po[kk][c];
    }
  __syncthreads();
  float* off_lds = smem + 16384;        // [4][256]
#pragma unroll
  for (int it = 0; it < 4; ++it) {
    const int idx = tid + it * 256;
    const int kk = idx >> 8, col = idx & 255;
    float sum = b2[kk];
#pragma unroll
    for (int t2 = 0; t2 < 16; ++t2) sum += po_lds[((t2 * 4 + kk) * 256) + col];
    off_lds[kk * 256 + col] = sum;
  }
  __syncthreads();
  {
    const int n = n0 + tid;
    const float* sx = xyz + ((size_t)b * NTOT + n) * 3;
    float4 o;
    o.x = sx[0] + off_lds[0 * 256 + tid];
    o.y = sx[1] + off_lds[1 * 256 + tid];
    o.z = sx[2] + off_lds[2 * 256 + tid];
    o.w = off_lds[3 * 256 + tid];
    *(float4*)(prop + ((size_t)b * NTOT + n) * 4) = o;
  }
#undef A_ROW
#undef A_SRC
#undef A_DST
#undef B_SRC
#undef B_DST
}

// ---------------------------------------------------------------------------
// shared clip routine: register-only Sutherland-Hodgman, 8-slot cndmask push
// chains (exact reference semantics incl. OOB drop / gather clamp).
// ---------------------------------------------------------------------------
__device__ __forceinline__ float polyclip_reg(
    float s0x, float s0y, float s1x, float s1y,
    float s2x, float s2y, float s3x, float s3y,
    const float cjx[4], const float cjy[4]) {
#pragma clang fp contract(off)
  float vx[8], vy[8];
  vx[0] = s0x; vy[0] = s0y; vx[1] = s1x; vy[1] = s1y;
  vx[2] = s2x; vy[2] = s2y; vx[3] = s3x; vy[3] = s3y;
#pragma unroll
  for (int v = 4; v < 8; ++v) { vx[v] = 0.f; vy[v] = 0.f; }
  int cnt = 4;
#pragma unroll
  for (int e = 0; e < 4; ++e) {
    const float ax = cjx[e], ay = cjy[e];
    const float bx = cjx[(e + 1) & 3], by = cjy[(e + 1) & 3];
    const float nx = bx - ax, ny = by - ay;
    float d[8];
#pragma unroll
    for (int v = 0; v < 8; ++v) d[v] = nx * (vy[v] - ay) - ny * (vx[v] - ax);
    float ox[8], oy[8];
#pragma unroll
    for (int v = 0; v < 8; ++v) { ox[v] = 0.f; oy[v] = 0.f; }
    int oc = 0;
#pragma unroll
    for (int v = 0; v < 8; ++v) {
      const bool valid = v < cnt;
      float nvx, nvy, dn;
      if (v == 7) {
        const bool big = cnt > 8;
        nvx = big ? vx[7] : vx[0]; nvy = big ? vy[7] : vy[0]; dn = big ? d[7] : d[0];
      } else {
        const bool wrap = (v + 1 >= cnt);
        nvx = wrap ? vx[0] : vx[v + 1];
        nvy = wrap ? vy[0] : vy[v + 1];
        dn  = wrap ? d[0]  : d[v + 1];
      }
      const float dc = d[v];
      const bool inc = dc >= 0.f, inn = dn >= 0.f;
      const bool e1 = valid && inc;
#pragma unroll
      for (int s2 = 0; s2 < 8; ++s2) {
        const bool w_ = e1 && (oc == s2);
        ox[s2] = w_ ? vx[v] : ox[s2];
        oy[s2] = w_ ? vy[v] : oy[s2];
      }
      oc += e1 ? 1 : 0;
      const bool e2 = valid && (inc != inn);
      const float den = dc - dn;
      const float t = dc / ((den == 0.f) ? 1.0f : den);
      const float ipx = vx[v] + t * (nvx - vx[v]);
      const float ipy = vy[v] + t * (nvy - vy[v]);
#pragma unroll
      for (int s2 = 0; s2 < 8; ++s2) {
        const bool w_ = e2 && (oc == s2);
        ox[s2] = w_ ? ipx : ox[s2];
        oy[s2] = w_ ? ipy : oy[s2];
      }
      oc += e2 ? 1 : 0;
    }
#pragma unroll
    for (int v = 0; v < 8; ++v) { vx[v] = ox[v]; vy[v] = oy[v]; }
    cnt = oc;
  }
  float s = 0.f;
#pragma unroll
  for (int v = 0; v < 8; ++v) {
    const bool valid = (v < cnt) && (cnt >= 3);
    float jx, jy;
    if (v == 7) {
      const bool big = cnt > 8;
      jx = big ? vx[7] : vx[0]; jy = big ? vy[7] : vy[0];
    } else {
      const bool wrap = (v + 1 >= cnt);
      jx = wrap ? vx[0] : vx[v + 1]; jy = wrap ? vy[0] : vy[v + 1];
    }
    s += valid ? (vx[v] * jy - jx * vy[v]) : 0.f;
  }
  return fabsf(s) * 0.5f;
}

__device__ __forceinline__ bool pair_suppressed(
    const float* __restrict__ corners, const float* __restrict__ areas,
    int b, int i, int j) {
  const float* ci = corners + ((size_t)b * NPRE + i) * 8;
  const float* cj = corners + ((size_t)b * NPRE + j) * 8;
  float cjx[4], cjy[4];
#pragma unroll
  for (int q = 0; q < 4; ++q) { cjx[q] = cj[2 * q]; cjy[q] = cj[2 * q + 1]; }
  const float inter = polyclip_reg(ci[0], ci[1], ci[2], ci[3],
                                   ci[4], ci[5], ci[6], ci[7], cjx, cjy);
  const float ai = areas[(size_t)b * NPRE + i];
  const float aj = areas[(size_t)b * NPRE + j];
  const float iou = inter / fmaxf(ai + aj - inter, 1e-8f);
  return iou > 0.85f;
}

// ---------------------------------------------------------------------------
// K2: exact top-NPRE selection via threshold bisection on sigmoid bits with
//     early exit; bitonic sort of <=1024 candidates (key<<32 | ~idx).
//     Emits corners/area/aabb and zeroes the pairgen worklist counters.
// ---------------------------------------------------------------------------
__global__ __launch_bounds__(1024) void select_kernel(
    const float* __restrict__ cla, const float* __restrict__ prop,
    const float* __restrict__ tmpl, float* __restrict__ selbox,
    float* __restrict__ corners, float* __restrict__ areas,
    float* __restrict__ aabb, int* __restrict__ wlcnt) {
  __shared__ unsigned red[17];
  __shared__ int cnt_lds;
  __shared__ unsigned long long cand[1024];
  const int b = blockIdx.x, tid = threadIdx.x;
  if (tid == 0) wlcnt[b] = 0;
  unsigned key[16];
#pragma unroll
  for (int q = 0; q < 16; ++q) {
    const float x = cla[(size_t)b * NTOT + q * 1024 + tid];
    key[q] = __float_as_uint(1.0f / (1.0f + expf(-x)));
  }
  unsigned lo = 0u, hi = 0xFFFFFFFFu;
  unsigned T = 0u;
  bool done = false;
  while (!done && (hi - lo > 1u)) {
    const unsigned mid = lo + ((hi - lo) >> 1);
    int c = 0;
#pragma unroll
    for (int q = 0; q < 16; ++q) c += (key[q] >= mid) ? 1 : 0;
#pragma unroll
    for (int off = 32; off > 0; off >>= 1) c += __shfl_down(c, off);
    __syncthreads();
    if ((tid & 63) == 0) red[tid >> 6] = (unsigned)c;
    __syncthreads();
    if (tid == 0) {
      unsigned s = 0;
      for (int w2 = 0; w2 < 16; ++w2) s += red[w2];
      red[16] = s;
    }
    __syncthreads();
    const unsigned cntv = red[16];
    if (cntv >= NPRE && cntv <= 1024) { T = mid; done = true; }
    else if (cntv >= NPRE) lo = mid;
    else hi = mid;
  }
  if (!done) T = lo;
  if (tid == 0) cnt_lds = 0;
  cand[tid] = 0ull;
  __syncthreads();
#pragma unroll
  for (int q = 0; q < 16; ++q) {
    if (key[q] >= T) {
      const int pos = atomicAdd(&cnt_lds, 1);
      if (pos < 1024)
        cand[pos] = ((unsigned long long)key[q] << 32) |
                    (unsigned long long)(0xFFFFFFFFu - (unsigned)(q * 1024 + tid));
    }
  }
  __syncthreads();
  for (int k = 2; k <= 1024; k <<= 1) {
    for (int j = k >> 1; j > 0; j >>= 1) {
      if (tid < 512) {
        const int i = ((tid & ~(j - 1)) << 1) | (tid & (j - 1));
        const int l = i | j;
        const unsigned long long Pi = cand[i], Pl = cand[l];
        const bool asc = (i & k) == 0;
        if ((Pi < Pl) == asc) { cand[i] = Pl; cand[l] = Pi; }
      }
      __syncthreads();
    }
  }
  if (tid < NPRE) {
    const unsigned long long p = cand[tid];
    const int idx = (int)(0xFFFFFFFFu - (unsigned)(p & 0xFFFFFFFFull));
    const float score = __uint_as_float((unsigned)(p >> 32));
    const float4 pv = *(const float4*)(prop + ((size_t)b * NTOT + idx) * 4);
    const float d3 = tmpl[b * 7 + 3], d4 = tmpl[b * 7 + 4], d5 = tmpl[b * 7 + 5];
    const size_t o8 = ((size_t)b * NPRE + tid) * 8;
    selbox[o8 + 0] = pv.x; selbox[o8 + 1] = pv.y; selbox[o8 + 2] = pv.z;
    selbox[o8 + 3] = d3;   selbox[o8 + 4] = d4;   selbox[o8 + 5] = d5;
    selbox[o8 + 6] = pv.w; selbox[o8 + 7] = score;
    {
#pragma clang fp contract(off)
      const float cu = pv.x, cv = pv.z;
      const float hl = d5 * 0.5f, hw = d4 * 0.5f;
      const float x1 = cu - hl, y1 = cv - hw, x2 = cu + hl, y2 = cv + hw;
      const float cx = (x1 + x2) * 0.5f, cy = (y1 + y2) * 0.5f;
      const float hx = (x2 - x1) * 0.5f, hy = (y2 - y1) * 0.5f;
      const float cr = cosf(pv.w), sr = sinf(pv.w);
      const float lx[4] = {-hx, hx, hx, -hx};
      const float ly[4] = {-hy, -hy, hy, hy};
      float bx0 = 1e30f, by0 = 1e30f, bx1 = -1e30f, by1 = -1e30f;
#pragma unroll
      for (int q = 0; q < 4; ++q) {
        const float X = cx + cr * lx[q] - sr * ly[q];
        const float Y = cy + sr * lx[q] + cr * ly[q];
        corners[o8 + 2 * q]     = X;
        corners[o8 + 2 * q + 1] = Y;
        bx0 = fminf(bx0, X); by0 = fminf(by0, Y);
        bx1 = fmaxf(bx1, X); by1 = fmaxf(by1, Y);
      }
      areas[(size_t)b * NPRE + tid] = (x2 - x1) * (y2 - y1);
      float4 bb; bb.x = bx0; bb.y = by0; bb.z = bx1; bb.w = by1;
      *(float4*)(aabb + ((size_t)b * NPRE + tid) * 4) = bb;
    }
  }
}

// ---------------------------------------------------------------------------
// K3a: pairgen — AABB quick-test (conservative, margin >> fp noise), compact
// passing pairs into per-batch worklist; zero own sup row. Overflow pairs
// are clipped inline (correctness guard).
// ---------------------------------------------------------------------------
__global__ __launch_bounds__(256) void pairgen_kernel(
    const float* __restrict__ aabb, const float* __restrict__ areas,
    const float* __restrict__ corners, unsigned long long* __restrict__ sup,
    unsigned* __restrict__ wl, int* __restrict__ wlcnt, int cap) {
  __shared__ int wsum[4];
  __shared__ int base_s;
  const int i = blockIdx.x, b = blockIdx.y, tid = threadIdx.x;
  if (tid < 16) sup[((size_t)b * NPRE + i) * 16 + tid] = 0ull;
  const float4 bi = *(const float4*)(aabb + ((size_t)b * NPRE + i) * 4);
  const float ai = areas[(size_t)b * NPRE + i];
  bool pass[4];
  int pc = 0;
#pragma unroll
  for (int c = 0; c < 4; ++c) {
    const int j = c * 256 + tid;
    bool p = false;
    if (j > i && j < NPRE) {
      const float4 bj = *(const float4*)(aabb + ((size_t)b * NPRE + j) * 4);
      const float aj = areas[(size_t)b * NPRE + j];
      const float ow = fminf(bi.z, bj.z) - fmaxf(bi.x, bj.x);
      const float oh = fminf(bi.w, bj.w) - fmaxf(bi.y, bj.y);
      const float ov = fmaxf(ow, 0.f) * fmaxf(oh, 0.f);
      p = (ov >= 0.45f * (ai + aj));
    }
    pass[c] = p;
    pc += p ? 1 : 0;
  }
  int inc = pc;
#pragma unroll
  for (int d2 = 1; d2 < 64; d2 <<= 1) {
    const int u = __shfl_up(inc, d2);
    if ((tid & 63) >= d2) inc += u;
  }
  if ((tid & 63) == 63) wsum[tid >> 6] = inc;
  __syncthreads();
  if (tid == 0) {
    const int tot = wsum[0] + wsum[1] + wsum[2] + wsum[3];
    base_s = (tot > 0) ? atomicAdd(&wlcnt[b], tot) : 0;
  }
  __syncthreads();
  int wbase = 0;
#pragma unroll
  for (int w = 0; w < 4; ++w)
    if (w < (tid >> 6)) wbase += wsum[w];
  int myoff = base_s + wbase + (inc - pc);
#pragma unroll
  for (int c = 0; c < 4; ++c) {
    if (pass[c]) {
      const int j = c * 256 + tid;
      const int pos = myoff++;
      if (pos < cap) {
        wl[(size_t)b * cap + pos] = (unsigned)((i << 10) | j);
      } else {
        if (pair_suppressed(corners, areas, b, i, j))
          atomicOr(&sup[((size_t)b * NPRE + i) * 16 + (j >> 6)],
                   1ull << (j & 63));
      }
    }
  }
}

// ---------------------------------------------------------------------------
// K3b: clip — dense worklist, one pair per lane, exact clip, atomicOr bit.
// ---------------------------------------------------------------------------
__global__ __launch_bounds__(256) void clip_kernel(
    const float* __restrict__ corners, const float* __restrict__ areas,
    const unsigned* __restrict__ wl, const int* __restrict__ wlcnt, int cap,
    unsigned long long* __restrict__ sup) {
  const int b = blockIdx.y, tid = threadIdx.x;
  const int n = min(wlcnt[b], cap);
  for (int idx = blockIdx.x * 256 + tid; idx < n; idx += gridDim.x * 256) {
    const unsigned e = wl[(size_t)b * cap + idx];
    const int i = (int)(e >> 10), j = (int)(e & 1023u);
    if (pair_suppressed(corners, areas, b, i, j))
      atomicOr(&sup[((size_t)b * NPRE + i) * 16 + (j >> 6)], 1ull << (j & 63));
  }
}

// ---------------------------------------------------------------------------
// K4: sequential NMS. LDS-staged sup matrix, 4-deep static prefetch.
// ---------------------------------------------------------------------------
#define NMS_ROWS 904
__global__ __launch_bounds__(1024) void nms_kernel(
    const unsigned long long* __restrict__ sup,
    unsigned long long* __restrict__ keepw) {
  extern __shared__ unsigned long long rows[];   // NMS_ROWS*16*8 = 115,712 B
  const int b = blockIdx.x, tid = threadIdx.x;
  const unsigned long long* srow = sup + (size_t)b * NPRE * 16;
  for (int q = tid; q < NMS_ROWS * 16; q += 1024)
    rows[q] = (q < NPRE * 16) ? srow[q] : 0ull;
  __syncthreads();
  if (tid < 64) {
    const int lane = tid;
    const bool ld = lane < 16;
    unsigned long long kw = 0ull;
    if (lane < 14) kw = ~0ull;
    else if (lane == 14) kw = 0xFull;            // bits 896..899
    unsigned long long r0 = ld ? rows[0 * 16 + lane] : 0ull;
    unsigned long long r1 = ld ? rows[1 * 16 + lane] : 0ull;
    unsigned long long r2 = ld ? rows[2 * 16 + lane] : 0ull;
    unsigned long long r3 = ld ? rows[3 * 16 + lane] : 0ull;
#define NMS_STEP(ii, bufv)                                            \
    {                                                                 \
      const unsigned long long w = __shfl(kw, (ii) >> 6);             \
      if ((w >> ((ii) & 63)) & 1ull) kw &= ~(bufv);                   \
      bufv = ld ? rows[((ii) + 4) * 16 + lane] : 0ull;                \
    }
    for (int i = 0; i < NPRE; i += 4) {
      NMS_STEP(i + 0, r0)
      NMS_STEP(i + 1, r1)
      NMS_STEP(i + 2, r2)
      NMS_STEP(i + 3, r3)
    }
#undef NMS_STEP
    if (lane < 15) keepw[b * 16 + lane] = kw;
  }
}

// ---------------------------------------------------------------------------
// K5: zero outputs, rank kept boxes, scatter top-64.
// ---------------------------------------------------------------------------
__global__ __launch_bounds__(128) void out_kernel(
    const float* __restrict__ selbox,
    const unsigned long long* __restrict__ keepw, float* __restrict__ out) {
  const int b = blockIdx.x, t = threadIdx.x;
  float* retb = out + (size_t)b * (NPOST * 7);
  float* rets = out + (size_t)NBATCH * NPOST * 7 + (size_t)b * NPOST;
  float* cent = out + (size_t)NBATCH * NPOST * 7 + (size_t)NBATCH * NPOST +
                (size_t)NBATCH * NTOT * 4 + (size_t)b * (NPOST * 3);
  for (int q = t; q < NPOST * 7; q += 128) retb[q] = 0.f;
  if (t < NPOST) rets[t] = 0.f;
  for (int q = t; q < NPOST * 3; q += 128) cent[q] = 0.f;
  __syncthreads();
  if (t < 64) {
    const unsigned long long kws = (t < 15) ? keepw[b * 16 + t] : 0ull;
    const int pc = __popcll(kws);
    int inc = pc;
    for (int d2 = 1; d2 < 64; d2 <<= 1) {
      const int up = __shfl_up(inc, d2);
      if (t >= d2) inc += up;
    }
    const int ex = inc - pc;
    for (int it = 0; it < 15; ++it) {
      const int i = t + it * 64;
      const int w = (i >> 6) & 63;
      const unsigned long long kword = __shfl(kws, w);
      const int exw = __shfl(ex, w);
      if (i < NPRE) {
        const int bp = i & 63;
        if ((kword >> bp) & 1ull) {
          const int rank =
              exw + __popcll(kword & (((unsigned long long)1 << bp) - 1ull));
          if (rank < NPOST) {
            const float* sb = selbox + ((size_t)b * NPRE + i) * 8;
#pragma unroll
            for (int c = 0; c < 7; ++c) retb[rank * 7 + c] = sb[c];
            rets[rank] = sb[7];
            cent[rank * 3 + 0] = sb[0];
            cent[rank * 3 + 1] = sb[1];
            cent[rank * 3 + 2] = sb[2];
          }
        }
      }
    }
  }
}

// ---------------------------------------------------------------------------
extern "C" void kernel_launch(void* const* d_in, const int* in_sizes, int n_in,
                              void* d_out, int out_size, void* d_ws, size_t ws_size,
                              hipStream_t stream) {
  const float* xyz   = (const float*)d_in[0];
  const float* feat  = (const float*)d_in[1];
  const float* cla   = (const float*)d_in[2];
  const float* tmpl  = (const float*)d_in[3];
  const float* W1    = (const float*)d_in[4];
  const float* b1    = (const float*)d_in[5];
  const float* gamma = (const float*)d_in[6];
  const float* beta  = (const float*)d_in[7];
  const float* rmean = (const float*)d_in[8];
  const float* rvar  = (const float*)d_in[9];
  const float* W2    = (const float*)d_in[10];
  const float* b2    = (const float*)d_in[11];
  float* out  = (float*)d_out;
  float* prop = out + (size_t)NBATCH * NPOST * 7 + (size_t)NBATCH * NPOST;

  char* ws = (char*)d_ws;
  float* selbox  = (float*)(ws);                                   // 230400 B
  float* corners = (float*)(ws + 230400);                          // 230400 B
  float* areas   = (float*)(ws + 460800);                          // 28800 B
  float* aabb    = (float*)(ws + 489600);                          // 115200 B
  unsigned long long* sup   = (unsigned long long*)(ws + 604800);  // 921600 B
  unsigned long long* keepw = (unsigned long long*)(ws + 1526400); // 1024 B
  int* wlcnt = (int*)(ws + 1527424);                               // 32 B
  unsigned* wl = (unsigned*)(ws + 1527456);
  long long avail = (long long)ws_size - 1527456;
  if (avail < 0) avail = 0;
  int cap = (int)(avail / (4 * NBATCH));
  if (cap > 404551) cap = 404551;   // max j>i pairs per batch

  // 69632 B = 17408 floats: compute dbuf 12288 f + epilogue 16384+1024 f
  // (epilogue reuses [0..16384); off_lds at 16384..17408). 2 blocks/CU.
  (void)hipFuncSetAttribute((const void*)mlp_kernel,
                            hipFuncAttributeMaxDynamicSharedMemorySize, 69632);
  mlp_kernel<<<dim3(NTOT / 256, NBATCH), 256, 69632, stream>>>(
      feat, xyz, W1, b1, gamma, beta, rmean, rvar, W2, b2, prop);

  select_kernel<<<NBATCH, 1024, 0, stream>>>(cla, prop, tmpl, selbox, corners,
                                             areas, aabb, wlcnt);

  pairgen_kernel<<<dim3(NPRE, NBATCH), 256, 0, stream>>>(
      aabb, areas, corners, sup, wl, wlcnt, cap);

  clip_kernel<<<dim3(64, NBATCH), 256, 0, stream>>>(corners, areas, wl, wlcnt,
                                                    cap, sup);

  (void)hipFuncSetAttribute((const void*)nms_kernel,
                            hipFuncAttributeMaxDynamicSharedMemorySize,
                            NMS_ROWS * 16 * (int)sizeof(unsigned long long));
  nms_kernel<<<NBATCH, 1024, NMS_ROWS * 16 * sizeof(unsigned long long),
               stream>>>(sup, keepw);

  out_kernel<<<NBATCH, 128, 0, stream>>>(selbox, keepw, out);
}